// Round 15
// baseline (18726.776 us; speedup 1.0000x reference)
//
#include <hip/hip_runtime.h>

// shallowPLRNN on MI355X — round 13 (resubmit): dual-subject interleaved schedule.
// Evidence: three barrier mechanisms (agent fences / L1-inv / L2 flags) all
// measure 10.6-11.2 ms => waits dominate and are mechanism-independent.
// Fix: hide the waits instead of cheapening them. Each subject is split over
// 16 blocks (half-size weight slices); each block holds TWO subjects
// (sB = sA^8, same XCD under round-robin) and interleaves their phases so
// every inter-block wait is preceded by ~half a step of independent sibling
// work. Flag protocol = round-9-verified light path (volatile store +
// {buffer_inv; volatile load} poll) with heavy cross-XCD fallback.
//   flag1[s][j]=g : block j stored hidg_s for step g-1   (wait before phaseB)
//   flag2[s][j]=g : z_s state generation g ready          (wait before stage)
// Per-block step: [stageA phaseA_A hidgA sig1A] [stageB phaseA_B hidgB sig1B]
//                 [decodeA] [wait1A phaseB_A reduceA sig2A]
//                 [wait1B phaseB_B reduceB sig2B]

typedef _Float16 f16;
typedef _Float16 f16x8 __attribute__((ext_vector_type(8)));
typedef float f32x4 __attribute__((ext_vector_type(4)));

#define TSTEPS 1024

// ---- workspace byte offsets (total 2382080 bytes ~= 2.27 MB) ----
#define WS_C     0ul          // C table: 64x64 fp32
#define WS_ZG    16384ul      // z state: 16 subj x 48 x 256 fp32
#define WS_HIDG  802816ul     // hidden exchange: 16 subj x 48 x 1024 f16
#define WS_ORDER 2375680ul    // sample order (256 int)
#define WS_CNT   2376704ul    // per-subject count (16 int)
#define WS_OFFS  2376768ul    // per-subject offset (16 int)
#define WS_CTR   2376832ul    // heavy counters: 16 x 128B ([0]=flag1, [8]=flag2)
#define WS_GCTR  2378880ul    // global handshake counter (128B)
#define WS_XCC   2379008ul    // per-subject XCC ids (16 x 16 int)
#define WS_FLAG  2380032ul    // light flags: 16 x 128B ([0..15]=flag1, [16..31]=flag2)
#define WS_NEED  2382080ul

// ---- main-kernel static LDS layout (bytes, total 81280) ----
#define SM_ZPK_A  0           // [48][280] f16 post-TF z, subject A — aliased by red[]
#define SM_ZPK_B  26880       // [48][280] f16 post-TF z, subject B
#define SM_ZPRE_A 53760       // [48][72]  f16 raw z (k<64), A
#define SM_ZPRE_B 60672       // [48][72]  f16 raw z (k<64), B
#define SM_ZSL_A  67584       // [48][16]  fp32 post-TF z slice, A
#define SM_ZSL_B  70656       // [48][16]  fp32 post-TF z slice, B
#define SM_TBUF   73728       // [48][72]  f16 hidden slice (shared A/B, time-mux)
#define SM_AH_A   80640       // A[16],h1[16] fp32
#define SM_AH_B   80768
#define SM_ORD_A  80896       // [48] int
#define SM_ORD_B  81088
#define SM_SIZE   81280

__device__ __forceinline__ unsigned pack2f16(float x, float y) {
    union { f16 h[2]; unsigned u; } v;
    v.h[0] = (f16)x; v.h[1] = (f16)y;
    return v.u;
}

// signal: leading __syncthreads drains all waves' stores (compiler emits
// s_waitcnt vmcnt(0) before s_barrier — validated by rounds 3/12 passing).
__device__ __forceinline__ void sig_flag(int* c, int* f, int jf, int gen, bool light) {
    __syncthreads();
    if (threadIdx.x == 0) {
        if (light) {
            *(volatile int*)(f + jf) = gen;                  // write-through -> XCD L2
        } else {
            __builtin_amdgcn_fence(__ATOMIC_RELEASE, "agent");   // buffer_wbl2 sc1
            __hip_atomic_fetch_add(c, 1, __ATOMIC_RELAXED, __HIP_MEMORY_SCOPE_AGENT);
        }
    }
}

// wait: light = round-9-verified {buffer_inv; volatile load} poll by wave 0
// (16 flags, 4 lanes each); the inv before the successful observation also
// drops stale data lines. heavy = agent atomic poll + acquire fence.
__device__ __forceinline__ void wait_flag(int* c, int target, int* f, int gen, bool light) {
    if (light) {
        if (threadIdx.x < 64) {
            volatile const int* fp = (volatile const int*)(f + (threadIdx.x & 15));
            for (;;) {
                asm volatile("buffer_inv" ::: "memory");
                int v = *fp;
                if (__all(v >= gen)) break;
                __builtin_amdgcn_s_sleep(1);
            }
            asm volatile("buffer_inv" ::: "memory");
        }
    } else {
        if (threadIdx.x == 0) {
            while (__hip_atomic_load(c, __ATOMIC_RELAXED, __HIP_MEMORY_SCOPE_AGENT) < target)
                __builtin_amdgcn_s_sleep(1);
            __builtin_amdgcn_fence(__ATOMIC_ACQUIRE, "agent");
        }
    }
    __syncthreads();
}

// ---------- prep: C = (M^T M)^-1 M[:64,:]^T  (64x64), fp32 Gauss-Jordan ----------
__global__ __launch_bounds__(256) void prep_kernel(const float* __restrict__ M,
                                                   float* __restrict__ C) {
    __shared__ float aug[64 * 132];
    __shared__ float fac[64];
    int tid = threadIdx.x;
    {
        int i = tid >> 2;
        int j0 = (tid & 3) * 16;
        float acc[16];
        #pragma unroll
        for (int e = 0; e < 16; ++e) acc[e] = 0.f;
        for (int r = 0; r < 256; ++r) {
            float mi = M[r*64 + i];
            #pragma unroll
            for (int e = 0; e < 16; ++e) acc[e] += mi * M[r*64 + j0 + e];
        }
        #pragma unroll
        for (int e = 0; e < 16; ++e) aug[i*132 + j0 + e] = acc[e];
    }
    for (int idx = tid; idx < 4096; idx += 256) {
        int x = idx >> 6, c = idx & 63;
        aug[x*132 + 64 + c] = M[c*64 + x];
    }
    __syncthreads();
    for (int p = 0; p < 64; ++p) {
        float piv = aug[p*132 + p];
        __syncthreads();
        if (tid < 128) aug[p*132 + tid] /= piv;
        __syncthreads();
        if (tid < 64) fac[tid] = aug[tid*132 + p];
        __syncthreads();
        for (int idx = tid; idx < 8192; idx += 256) {
            int r = idx >> 7, c = idx & 127;
            if (r != p) aug[r*132 + c] -= fac[r] * aug[p*132 + c];
        }
        __syncthreads();
    }
    for (int idx = tid; idx < 4096; idx += 256) {
        int x = idx >> 6, c = idx & 63;
        C[x*64 + c] = aug[x*132 + 64 + c];
    }
}

// ---------- forcing: out[b][t][0:64] = x[b][t][:] @ C ----------
__global__ __launch_bounds__(256) void forcing_kernel(const float* __restrict__ x,
        const float* __restrict__ C, float* __restrict__ fout) {
    __shared__ float xs[64 * 68];
    __shared__ float Cs[64 * 64];
    int tid = threadIdx.x;
    for (int i = tid; i < 1024; i += 256)
        ((float4*)Cs)[i] = ((const float4*)C)[i];
    long r0 = (long)blockIdx.x * 64;
    int b  = (int)(r0 >> 10);
    int t0 = (int)(r0 & 1023);
    const float4* xb = (const float4*)(x + ((long)b * 1024 + t0) * 64);
    for (int i = tid; i < 1024; i += 256) {
        float4 v = xb[i];
        int row = i >> 4, col = (i & 15) * 4;
        *(float4*)&xs[row*68 + col] = v;
    }
    __syncthreads();
    int row = tid >> 2, cg = (tid & 3) * 16;
    float acc[16];
    #pragma unroll
    for (int e = 0; e < 16; ++e) acc[e] = 0.f;
    for (int k = 0; k < 64; ++k) {
        float xv = xs[row*68 + k];
        const float* cr = &Cs[k*64 + cg];
        #pragma unroll
        for (int e = 0; e < 16; ++e) acc[e] += xv * cr[e];
    }
    float4* dst = (float4*)(fout + ((size_t)b*1024 + t0 + row)*64 + cg);
    #pragma unroll
    for (int e = 0; e < 4; ++e) {
        float4 v; v.x = acc[4*e]; v.y = acc[4*e+1]; v.z = acc[4*e+2]; v.w = acc[4*e+3];
        dst[e] = v;
    }
}

// ---------- grouping: bucket samples by subject, zero counters/flags ----------
__global__ __launch_bounds__(256) void group_kernel(const int* __restrict__ subject,
        int* order, int* cnt, int* offs, int* ctr, int* flag, int* gctr) {
    __shared__ int lc[16], lo[16], cur[16];
    int tid = threadIdx.x;
    if (tid < 16) { lc[tid] = 0; cur[tid] = 0; }
    __syncthreads();
    int s = subject[tid];
    atomicAdd(&lc[s], 1);
    __syncthreads();
    if (tid == 0) { int a = 0; for (int i = 0; i < 16; ++i) { lo[i] = a; a += lc[i]; } }
    __syncthreads();
    int pos = lo[s] + atomicAdd(&cur[s], 1);
    order[pos] = tid;
    if (tid < 16) {
        cnt[tid] = lc[tid]; offs[tid] = lo[tid];
        ctr[tid*32] = 0;          // flag1 heavy counter
        ctr[tid*32 + 8] = 0;      // flag2 heavy counter
        #pragma unroll
        for (int k = 0; k < 32; ++k) flag[tid*32 + k] = 0;   // light flags
    }
    if (tid == 0) gctr[0] = 0;
}

// ---------- per-subject building blocks ----------
template<int NT>
__device__ __forceinline__ void stage_subj(int t, int jX, int Bs, const int* ordl,
    const float* zgs, f16* zpk, f16* zpre, float* zsl, const float* out)
{
    int tid = threadIdx.x;
    int half = tid >> 7;
    int kk = (tid & 127) * 2;
    int kl = kk - 16*jX;
    #pragma unroll
    for (int i = 0; i < NT*8; ++i) {
        int n = i*2 + half;
        float zx = 0.f, zy = 0.f;
        if (n < Bs) {
            float2 zz = *(const float2*)&zgs[n*256 + kk];
            zx = zz.x; zy = zz.y;
        }
        float px = zx, py = zy;
        if (kk < 64) {
            ((unsigned*)zpre)[n*36 + (kk>>1)] = pack2f16(zx, zy);
            if (t < TSTEPS && n < Bs) {
                float2 fv = *(const float2*)&out[((size_t)ordl[n]*1024 + t)*64 + kk];
                px = 0.2f*fv.x + 0.8f*zx;
                py = 0.2f*fv.y + 0.8f*zy;
            }
        }
        ((unsigned*)zpk)[n*140 + (kk>>1)] = pack2f16(px, py);
        if (kl >= 0 && kl < 16) {
            float2 pv; pv.x = px; pv.y = py;
            *(float2*)&zsl[n*16 + kl] = pv;
        }
    }
}

template<int NT>
__device__ __forceinline__ void phaseA_subj(const f16x8 (&w2f)[8], const float (&h2v)[4],
    const f16* zpk, f16* tbuf, int w, int q, int li)
{
    const f32x4 zero4 = {0.f, 0.f, 0.f, 0.f};
    f32x4 acc[NT];
    #pragma unroll
    for (int nt = 0; nt < NT; ++nt) acc[nt] = zero4;
    #pragma unroll
    for (int nt = 0; nt < NT; ++nt)
        #pragma unroll
        for (int kt = 0; kt < 8; ++kt) {
            f16x8 bf = *(const f16x8*)&zpk[(16*nt + li)*280 + kt*32 + q*8];
            acc[nt] = __builtin_amdgcn_mfma_f32_16x16x32_f16(w2f[kt], bf, acc[nt], 0,0,0);
        }
    #pragma unroll
    for (int nt = 0; nt < NT; ++nt)
        #pragma unroll
        for (int r = 0; r < 4; ++r) {
            float hv = acc[nt][r] + h2v[r];
            hv = hv > 0.f ? hv : 0.f;
            tbuf[(nt*16 + li)*72 + 16*w + 4*q + r] = (f16)hv;
        }
}

template<int NT>
__device__ __forceinline__ void hidg_store(int jX, const f16* tbuf, char* hgs) {
    for (int c = threadIdx.x; c < NT*128; c += 256) {
        int n = c >> 3, cc = c & 7;
        *(f16x8*)(hgs + n*2048 + jX*128 + cc*16) = *(const f16x8*)&tbuf[n*72 + cc*8];
    }
}

template<int NT>
__device__ __forceinline__ void decode_subj(int t, int jX, int Bs, const int* ordl,
    const f16* zpk, const f16* zpre, const f16x8 (&mfr)[8], float* out,
    int w, int q, int li)
{
    const f32x4 zero4 = {0.f, 0.f, 0.f, 0.f};
    f32x4 dacc = zero4;
    #pragma unroll
    for (int kt = 0; kt < 8; ++kt) {
        f16x8 af;
        if (kt < 2) af = *(const f16x8*)&zpre[(16*jX + li)*72 + kt*32 + q*8];
        else        af = *(const f16x8*)&zpk [(16*jX + li)*280 + kt*32 + q*8];
        dacc = __builtin_amdgcn_mfma_f32_16x16x32_f16(af, mfr[kt], dacc, 0, 0, 0);
    }
    #pragma unroll
    for (int r = 0; r < 4; ++r) {
        int n = 16*jX + q*4 + r;
        if (n < Bs)
            out[((size_t)ordl[n]*TSTEPS + (t-1))*64 + 16*w + li] = dacc[r];
    }
}

template<int NT>
__device__ __forceinline__ void phaseB_subj(const f16x8 (&w1f)[8], const char* hgs,
    float* red, int w, int q, int li, int lane)
{
    const f32x4 zero4 = {0.f, 0.f, 0.f, 0.f};
    f32x4 bacc[NT];
    #pragma unroll
    for (int nt = 0; nt < NT; ++nt) bacc[nt] = zero4;
    #pragma unroll
    for (int nt = 0; nt < NT; ++nt)
        #pragma unroll
        for (int kt = 0; kt < 8; ++kt) {
            f16x8 bf = *(const f16x8*)(hgs + (16*nt + li)*2048 + (8*w + kt)*64 + q*16);
            bacc[nt] = __builtin_amdgcn_mfma_f32_16x16x32_f16(w1f[kt], bf, bacc[nt], 0,0,0);
        }
    __syncthreads();   // prior readers of red's alias (zpk_A) are done
    #pragma unroll
    for (int nt = 0; nt < NT; ++nt)
        *(f32x4*)&red[(size_t)((w*NT + nt)*256 + lane*4)] = bacc[nt];
}

template<int NT>
__device__ __forceinline__ void reduce_subj(int jX, int Bs, const float* red,
    const float* zsl, const float* ah, float* zgs)
{
    for (int idx = threadIdx.x; idx < NT*256; idx += 256) {
        int n = idx >> 4, zdl = idx & 15;
        int qq = zdl >> 2, r = zdl & 3;
        int ln = qq*16 + (n & 15), nt = n >> 4;
        float sum = 0.f;
        #pragma unroll
        for (int ww = 0; ww < 4; ++ww)
            sum += red[(ww*NT + nt)*256 + ln*4 + r];
        float zv = ah[zdl] * zsl[n*16 + zdl] + sum + ah[16 + zdl];
        if (n < Bs) zgs[n*256 + 16*jX + zdl] = zv;
    }
}

template<int NT>
__device__ __forceinline__ void init_z0(int jX, int Bs, const int* ordl,
    const float* out, float* zgs)
{
    for (int idx = threadIdx.x; idx < NT*256; idx += 256) {
        int n = idx >> 4, zdl = idx & 15;
        int zd = 16*jX + zdl;
        float v = 0.f;
        if (zd < 64 && n < Bs) v = out[(size_t)ordl[n]*65536 + zd];
        zgs[n*256 + zd] = v;
    }
}

__device__ __forceinline__ void load_weights(int s, int jX,
    const float* W1t, const float* W2t, const float* h2t,
    f16x8 (&w2f)[8], f16x8 (&w1f)[8], float (&h2v)[4], int w, int q, int li)
{
    // W2 rows [64j,64j+64): wave w rows 16w..16w+16 ; K = full 256
    const float* src2 = W2t + (size_t)s*262144 + (size_t)(64*jX + 16*w + li)*256;
    #pragma unroll
    for (int kt = 0; kt < 8; ++kt) {
        int k0 = kt*32 + q*8;
        #pragma unroll
        for (int e = 0; e < 8; ++e) w2f[kt][e] = (f16)src2[k0+e];
    }
    // W1 rows [16j,16j+16) ; wave w K-chunk [256w,256w+256)
    const float* src1 = W1t + (size_t)s*262144 + (size_t)(16*jX + li)*1024 + 256*w;
    #pragma unroll
    for (int kt = 0; kt < 8; ++kt) {
        int k0 = kt*32 + q*8;
        #pragma unroll
        for (int e = 0; e < 8; ++e) w1f[kt][e] = (f16)src1[k0+e];
    }
    #pragma unroll
    for (int r = 0; r < 4; ++r)
        h2v[r] = h2t[s*1024 + 64*jX + 16*w + q*4 + r];
}

// ---------- main persistent kernel: 128 blocks, each runs 2 subjects ----------
template<int NTA, int NTB>
__device__ void run_pair(
    int sA, int jA, int BsA, int offA, bool doA, bool lightA,
    int sB, int jB, int BsB, int offB, bool doB, bool lightB,
    const float* __restrict__ W1t, const float* __restrict__ W2t,
    const float* __restrict__ At,  const float* __restrict__ h1t,
    const float* __restrict__ h2t, const float* __restrict__ Mt,
    float* __restrict__ zg, f16* __restrict__ hidg,
    const int* __restrict__ order, int* ctr, int* flag, float* out, char* sm)
{
    f16*   zpkA  = (f16*)(sm + SM_ZPK_A);
    f16*   zpkB  = (f16*)(sm + SM_ZPK_B);
    f16*   zpreA = (f16*)(sm + SM_ZPRE_A);
    f16*   zpreB = (f16*)(sm + SM_ZPRE_B);
    float* zslA  = (float*)(sm + SM_ZSL_A);
    float* zslB  = (float*)(sm + SM_ZSL_B);
    f16*   tbuf  = (f16*)(sm + SM_TBUF);
    float* ahA   = (float*)(sm + SM_AH_A);
    float* ahB   = (float*)(sm + SM_AH_B);
    int*   ordlA = (int*)(sm + SM_ORD_A);
    int*   ordlB = (int*)(sm + SM_ORD_B);
    float* red   = (float*)(sm + SM_ZPK_A);   // alias: zpk_A dead when red live

    const int tid  = threadIdx.x;
    const int w    = tid >> 6;
    const int lane = tid & 63;
    const int q    = lane >> 4;
    const int li   = lane & 15;

    float* zgsA = zg + (size_t)sA * (48*256);
    float* zgsB = zg + (size_t)sB * (48*256);
    char*  hgsA = (char*)hidg + (size_t)sA * 98304;
    char*  hgsB = (char*)hidg + (size_t)sB * 98304;
    int* c1A = ctr + sA*32;      int* c2A = ctr + sA*32 + 8;
    int* c1B = ctr + sB*32;      int* c2B = ctr + sB*32 + 8;
    int* f1A = flag + sA*32;     int* f2A = flag + sA*32 + 16;
    int* f1B = flag + sB*32;     int* f2B = flag + sB*32 + 16;

    if (tid < 48)                 ordlA[tid]    = (doA && tid < BsA) ? order[offA + tid] : 0;
    else if (tid < 96)            ordlB[tid-48] = (doB && (tid-48) < BsB) ? order[offB + tid-48] : 0;
    if (tid >= 128 && tid < 144)  ahA[tid-128]      = At [sA*256 + 16*jA + (tid-128)];
    if (tid >= 144 && tid < 160)  ahA[16 + tid-144] = h1t[sA*256 + 16*jA + (tid-144)];
    if (tid >= 160 && tid < 176)  ahB[tid-160]      = At [sB*256 + 16*jB + (tid-160)];
    if (tid >= 176 && tid < 192)  ahB[16 + tid-176] = h1t[sB*256 + 16*jB + (tid-176)];
    __syncthreads();

    f16x8 w2fA[8], w1fA[8], w2fB[8], w1fB[8], mfr[8];
    float h2vA[4], h2vB[4];
    load_weights(sA, jA, W1t, W2t, h2t, w2fA, w1fA, h2vA, w, q, li);
    load_weights(sB, jB, W1t, W2t, h2t, w2fB, w1fB, h2vB, w, q, li);
    #pragma unroll
    for (int kt = 0; kt < 8; ++kt)
        #pragma unroll
        for (int e = 0; e < 8; ++e)
            mfr[kt][e] = (f16)Mt[(kt*32 + q*8 + e)*64 + 16*w + li];

    if (doA) { init_z0<NTA>(jA, BsA, ordlA, out, zgsA); sig_flag(c2A, f2A, jA, 1, lightA); }
    if (doB) { init_z0<NTB>(jB, BsB, ordlB, out, zgsB); sig_flag(c2B, f2B, jB, 1, lightB); }

    for (int t = 0; t < TSTEPS; ++t) {
        if (doA) {
            wait_flag(c2A, 16*(t+1), f2A, t+1, lightA);
            stage_subj<NTA>(t, jA, BsA, ordlA, zgsA, zpkA, zpreA, zslA, out);
            __syncthreads();
            phaseA_subj<NTA>(w2fA, h2vA, zpkA, tbuf, w, q, li);
            __syncthreads();
            hidg_store<NTA>(jA, tbuf, hgsA);
            sig_flag(c1A, f1A, jA, t+1, lightA);
        }
        if (doB) {
            wait_flag(c2B, 16*(t+1), f2B, t+1, lightB);
            stage_subj<NTB>(t, jB, BsB, ordlB, zgsB, zpkB, zpreB, zslB, out);
            __syncthreads();
            phaseA_subj<NTB>(w2fB, h2vB, zpkB, tbuf, w, q, li);
            __syncthreads();
            hidg_store<NTB>(jB, tbuf, hgsB);
            sig_flag(c1B, f1B, jB, t+1, lightB);
        }
        if (doA && t > 0 && jA < NTA)
            decode_subj<NTA>(t, jA, BsA, ordlA, zpkA, zpreA, mfr, out, w, q, li);
        // (jB >= 8 > NTB: B-role never decodes)
        if (doA) {
            wait_flag(c1A, 16*(t+1), f1A, t+1, lightA);
            phaseB_subj<NTA>(w1fA, hgsA, red, w, q, li, lane);
            __syncthreads();
            reduce_subj<NTA>(jA, BsA, red, zslA, ahA, zgsA);
            sig_flag(c2A, f2A, jA, t+2, lightA);
        }
        if (doB) {
            wait_flag(c1B, 16*(t+1), f1B, t+1, lightB);
            phaseB_subj<NTB>(w1fB, hgsB, red, w, q, li, lane);
            __syncthreads();
            reduce_subj<NTB>(jB, BsB, red, zslB, ahB, zgsB);
            sig_flag(c2B, f2B, jB, t+2, lightB);
        }
    }
    // epilogue: decode out[T-1] (raw z_T, no TF) — only sA tiles decode
    if (doA && jA < NTA) {
        wait_flag(c2A, 16*(TSTEPS+1), f2A, TSTEPS+1, lightA);
        stage_subj<NTA>(TSTEPS, jA, BsA, ordlA, zgsA, zpkA, zpreA, zslA, out);
        __syncthreads();
        decode_subj<NTA>(TSTEPS, jA, BsA, ordlA, zpkA, zpreA, mfr, out, w, q, li);
    }
}

__global__ __launch_bounds__(256, 1) void main_kernel(
    const float* W1t, const float* W2t, const float* At, const float* h1t,
    const float* h2t, const float* Mt, float* zg, f16* hidg,
    const int* order, const int* cnt, const int* offs, int* ctr, int* gctr,
    int* xccg, int* flag, float* out)
{
    __shared__ __align__(16) char sm[SM_SIZE];
    int bid = blockIdx.x;
    int sA = bid & 15, jA = bid >> 4;          // j 0..7 (A role)
    int sB = sA ^ 8,   jB = 8 + jA;            // j 8..15 (B role); same bid%8 -> same XCD
    // subject s's 16 blocks: bids ≡ s (mod 16) give j0..7; bids ≡ s^8 give j8..15

    int xcc;
    asm volatile("s_getreg_b32 %0, hwreg(HW_REG_XCC_ID)" : "=s"(xcc));
    xcc &= 0xf;
    if (threadIdx.x == 0) { xccg[sA*16 + jA] = xcc; xccg[sB*16 + jB] = xcc; }
    // one-time global handshake over all 128 blocks (heavy, cross-XCD safe)
    __syncthreads();
    if (threadIdx.x == 0) {
        __builtin_amdgcn_fence(__ATOMIC_RELEASE, "agent");
        __hip_atomic_fetch_add(gctr, 1, __ATOMIC_RELAXED, __HIP_MEMORY_SCOPE_AGENT);
        while (__hip_atomic_load(gctr, __ATOMIC_RELAXED, __HIP_MEMORY_SCOPE_AGENT) < 128)
            __builtin_amdgcn_s_sleep(1);
        __builtin_amdgcn_fence(__ATOMIC_ACQUIRE, "agent");
    }
    __syncthreads();
    bool lightA = true, lightB = true;
    for (int i = 0; i < 16; ++i) {
        lightA = lightA && (xccg[sA*16 + i] == xcc);
        lightB = lightB && (xccg[sB*16 + i] == xcc);
    }

    int BsA = cnt[sA]; if (BsA > 48) BsA = 48;
    int BsB = cnt[sB]; if (BsB > 48) BsB = 48;
    bool doA = BsA > 0, doB = BsB > 0;
    if (!doA && !doB) return;
    int NTA = doA ? ((BsA + 15) >> 4) : 1;
    int NTB = doB ? ((BsB + 15) >> 4) : 1;
    int offA = offs[sA], offB = offs[sB];

    switch ((NTA-1)*3 + (NTB-1)) {
    case 0: run_pair<1,1>(sA,jA,BsA,offA,doA,lightA, sB,jB,BsB,offB,doB,lightB,
            W1t,W2t,At,h1t,h2t,Mt,zg,hidg,order,ctr,flag,out,sm); break;
    case 1: run_pair<1,2>(sA,jA,BsA,offA,doA,lightA, sB,jB,BsB,offB,doB,lightB,
            W1t,W2t,At,h1t,h2t,Mt,zg,hidg,order,ctr,flag,out,sm); break;
    case 2: run_pair<1,3>(sA,jA,BsA,offA,doA,lightA, sB,jB,BsB,offB,doB,lightB,
            W1t,W2t,At,h1t,h2t,Mt,zg,hidg,order,ctr,flag,out,sm); break;
    case 3: run_pair<2,1>(sA,jA,BsA,offA,doA,lightA, sB,jB,BsB,offB,doB,lightB,
            W1t,W2t,At,h1t,h2t,Mt,zg,hidg,order,ctr,flag,out,sm); break;
    case 4: run_pair<2,2>(sA,jA,BsA,offA,doA,lightA, sB,jB,BsB,offB,doB,lightB,
            W1t,W2t,At,h1t,h2t,Mt,zg,hidg,order,ctr,flag,out,sm); break;
    case 5: run_pair<2,3>(sA,jA,BsA,offA,doA,lightA, sB,jB,BsB,offB,doB,lightB,
            W1t,W2t,At,h1t,h2t,Mt,zg,hidg,order,ctr,flag,out,sm); break;
    case 6: run_pair<3,1>(sA,jA,BsA,offA,doA,lightA, sB,jB,BsB,offB,doB,lightB,
            W1t,W2t,At,h1t,h2t,Mt,zg,hidg,order,ctr,flag,out,sm); break;
    case 7: run_pair<3,2>(sA,jA,BsA,offA,doA,lightA, sB,jB,BsB,offB,doB,lightB,
            W1t,W2t,At,h1t,h2t,Mt,zg,hidg,order,ctr,flag,out,sm); break;
    default: run_pair<3,3>(sA,jA,BsA,offA,doA,lightA, sB,jB,BsB,offB,doB,lightB,
            W1t,W2t,At,h1t,h2t,Mt,zg,hidg,order,ctr,flag,out,sm); break;
    }
}

extern "C" void kernel_launch(void* const* d_in, const int* in_sizes, int n_in,
                              void* d_out, int out_size, void* d_ws, size_t ws_size,
                              hipStream_t stream) {
    const float* x    = (const float*)d_in[0];
    const int*   subj = (const int*)d_in[1];
    const float* Mt   = (const float*)d_in[2];
    const float* At   = (const float*)d_in[3];
    const float* W1t  = (const float*)d_in[4];
    const float* W2t  = (const float*)d_in[5];
    const float* h1t  = (const float*)d_in[6];
    const float* h2t  = (const float*)d_in[7];
    float* out = (float*)d_out;
    char*  ws  = (char*)d_ws;
    if (ws_size < WS_NEED) return;  // fail-soft (need ~2.27 MB)

    float* C     = (float*)(ws + WS_C);
    float* zg    = (float*)(ws + WS_ZG);
    f16*   hidg  = (f16*)(ws + WS_HIDG);
    int*   order = (int*)(ws + WS_ORDER);
    int*   cnt   = (int*)(ws + WS_CNT);
    int*   offs  = (int*)(ws + WS_OFFS);
    int*   ctr   = (int*)(ws + WS_CTR);
    int*   gctr  = (int*)(ws + WS_GCTR);
    int*   xccg  = (int*)(ws + WS_XCC);
    int*   flag  = (int*)(ws + WS_FLAG);

    prep_kernel<<<1, 256, 0, stream>>>(Mt, C);
    forcing_kernel<<<4096, 256, 0, stream>>>(x, C, out);
    group_kernel<<<1, 256, 0, stream>>>(subj, order, cnt, offs, ctr, flag, gctr);
    main_kernel<<<128, 256, 0, stream>>>(W1t, W2t, At, h1t, h2t, Mt,
                                         zg, hidg, order, cnt, offs, ctr, gctr,
                                         xccg, flag, out);
}